// Round 3
// baseline (702.752 us; speedup 1.0000x reference)
//
#include <hip/hip_runtime.h>
#include <stdint.h>

#define T_TOK 4096
#define DIMD  1024
#define HIDN  2048
#define NEXP  8
#define RMAX  9216   // 8192 slots + 8*128 max alignment padding

typedef float f32x4 __attribute__((ext_vector_type(4)));
typedef short s16x8 __attribute__((ext_vector_type(8)));

__device__ __forceinline__ uint16_t f2bf(float f) {
    uint32_t u = __builtin_bit_cast(uint32_t, f);
    u += 0x7fffu + ((u >> 16) & 1u);
    return (uint16_t)(u >> 16);
}
__device__ __forceinline__ float bf2f(uint32_t h) {
    return __builtin_bit_cast(float, h << 16);
}
__device__ __forceinline__ uint32_t pk2(float a, float b) {
    return (uint32_t)f2bf(a) | ((uint32_t)f2bf(b) << 16);
}
// swizzled LDS byte offset: 128B row pitch, XOR row bits into 16B-granule slot
__device__ __forceinline__ int swz(int r, int cbyte) {
    return r * 128 + (cbyte ^ ((r & 7) << 4));
}
// async global->LDS, 16B per lane, LDS dest = base + lane*16 (wave-uniform base)
__device__ __forceinline__ void gload16(const void* g, void* l) {
    __builtin_amdgcn_global_load_lds(
        (const __attribute__((address_space(1))) void*)g,
        (__attribute__((address_space(3))) void*)l, 16, 0, 0);
}
// Stage a 128x64 bf16 tile (16KB) into LDS with st-16 swizzle.
// LDS dest is linear (slot s at byte 16*s); global source is inverse-swizzled
// so that a swz(r,cb) read returns element (r, cb). 4 issues per lane.
__device__ __forceinline__ void stage128x64(const uint16_t* gbase, int ldk,
                                            char* lds, int wv, int lane) {
    #pragma unroll
    for (int i = 0; i < 4; ++i) {
        int s = (wv * 4 + i) * 64 + lane;
        int row = s >> 3;
        int cb = ((s & 7) << 4) ^ ((row & 7) << 4);
        gload16(gbase + (size_t)row * ldk + (cb >> 1), lds + ((wv * 4 + i) << 10));
    }
}

// ---------------- small kernels ----------------

struct CvtArgs {
    const float* s[7];
    uint16_t*    d[7];
    int          nq[7];
};

__global__ void cvt_all_kernel(CvtArgs a) {
    int base = blockIdx.x * blockDim.x + threadIdx.x;
    int stride = gridDim.x * blockDim.x;
    #pragma unroll
    for (int seg = 0; seg < 7; ++seg) {
        const float4* sp = (const float4*)a.s[seg];
        uint2* dp = (uint2*)a.d[seg];
        int n = a.nq[seg];
        for (int i = base; i < n; i += stride) {
            float4 v = sp[i];
            uint2 o; o.x = pk2(v.x, v.y); o.y = pk2(v.z, v.w);
            dp[i] = o;
        }
    }
}

__global__ void router_kernel(const float* __restrict__ x, const float* __restrict__ rw,
                              const float* __restrict__ bias,
                              int* __restrict__ sel, float* __restrict__ wgt) {
    int t = blockIdx.x;
    int lane = threadIdx.x;            // 64 threads = 1 wave
    int e = lane & 7, seg = lane >> 3; // 8 lanes per expert, 8 segments of 128
    const float* xr = x + (size_t)t * DIMD + seg * 128;
    const float* wr = rw + (size_t)e * DIMD + seg * 128;
    float s = 0.f;
    #pragma unroll 8
    for (int i = 0; i < 128; ++i) s += xr[i] * wr[i];
    s += __shfl_xor(s, 8, 64);
    s += __shfl_xor(s, 16, 64);
    s += __shfl_xor(s, 32, 64);
    __shared__ float lg[8];
    if (lane < 8) lg[lane] = s + bias[lane];
    __syncthreads();
    if (lane == 0) {
        float l0 = -1e30f; int i0 = 0;
        #pragma unroll
        for (int i = 0; i < 8; ++i) { float v = lg[i]; if (v > l0) { l0 = v; i0 = i; } }
        float l1 = -1e30f; int i1 = 0;
        #pragma unroll
        for (int i = 0; i < 8; ++i) { if (i == i0) continue; float v = lg[i]; if (v > l1) { l1 = v; i1 = i; } }
        float e1 = expf(l1 - l0);      // l0 >= l1 -> e1 <= 1
        float d = 1.f + e1;
        sel[t * 2] = i0; sel[t * 2 + 1] = i1;
        wgt[t * 2] = 1.f / d; wgt[t * 2 + 1] = e1 / d;
    }
}

__global__ void count_kernel(const int* __restrict__ sel, int* __restrict__ cnt) {
    int i = blockIdx.x * blockDim.x + threadIdx.x;
    if (i < T_TOK * 2) atomicAdd(&cnt[sel[i]], 1);
}

__global__ void offs_kernel(const int* __restrict__ cnt, int* __restrict__ offs) {
    if (threadIdx.x == 0 && blockIdx.x == 0) {
        int o = 0;
        for (int e = 0; e < NEXP; ++e) { offs[e] = o; o += (cnt[e] + 127) & ~127; }
        offs[NEXP] = o;
    }
}

__global__ void assign_kernel(const int* __restrict__ sel, const int* __restrict__ offs,
                              int* __restrict__ fill, int* __restrict__ row_of) {
    int i = blockIdx.x * blockDim.x + threadIdx.x;
    if (i < T_TOK * 2) {
        int e = sel[i];
        row_of[i] = offs[e] + atomicAdd(&fill[e], 1);
    }
}

__global__ void gather_kernel(const uint16_t* __restrict__ xb, const int* __restrict__ row_of,
                              uint16_t* __restrict__ Xg) {
    int slot = blockIdx.x;
    int pos = row_of[slot];
    int t = slot >> 1;
    const uint4* src = (const uint4*)(xb + (size_t)t * DIMD);
    uint4* dst = (uint4*)(Xg + (size_t)pos * DIMD);
    dst[threadIdx.x] = src[threadIdx.x];   // 128 thr * 16B = 2048B row
}

__global__ void combine_kernel(const uint16_t* __restrict__ H2g, const int* __restrict__ row_of,
                               const float* __restrict__ wgt, float* __restrict__ out) {
    int t = blockIdx.x;
    int c = threadIdx.x * 8;   // 128 threads * 8 cols
    int r0 = row_of[t * 2], r1 = row_of[t * 2 + 1];
    float w0 = wgt[t * 2], w1 = wgt[t * 2 + 1];
    uint4 a = *(const uint4*)(H2g + (size_t)r0 * DIMD + c);
    uint4 b = *(const uint4*)(H2g + (size_t)r1 * DIMD + c);
    float* o = out + (size_t)t * DIMD + c;
    o[0] += w0 * bf2f(a.x & 0xffffu) + w1 * bf2f(b.x & 0xffffu);
    o[1] += w0 * bf2f(a.x >> 16)     + w1 * bf2f(b.x >> 16);
    o[2] += w0 * bf2f(a.y & 0xffffu) + w1 * bf2f(b.y & 0xffffu);
    o[3] += w0 * bf2f(a.y >> 16)     + w1 * bf2f(b.y >> 16);
    o[4] += w0 * bf2f(a.z & 0xffffu) + w1 * bf2f(b.z & 0xffffu);
    o[5] += w0 * bf2f(a.z >> 16)     + w1 * bf2f(b.z >> 16);
    o[6] += w0 * bf2f(a.w & 0xffffu) + w1 * bf2f(b.w & 0xffffu);
    o[7] += w0 * bf2f(a.w >> 16)     + w1 * bf2f(b.w >> 16);
}

// ---------------- GEMM kernels ----------------
// 128x128 tile, BK=64, 4 waves in 2x2, each wave 64x64 via 4x4 frags of 16x16x32 MFMA.
// All operands bf16; staging via global_load_lds (linear LDS dest, inverse-swizzled src).
// Grid: x = col tile (fast -> weight panels pinned per XCD since ncol%8==0),
//       y = row tile (slow -> A panel shared by the 16 consecutive col blocks).

template<int ROUTED>
__global__ __launch_bounds__(256, 3)
void gemm13_kernel(const uint16_t* __restrict__ A,
                   const uint16_t* __restrict__ W1, const uint16_t* __restrict__ W3,
                   uint16_t* __restrict__ H, int ldh,
                   const int* __restrict__ offs) {
    __shared__ __align__(16) char lds[49152];
    char* As  = lds;
    char* B1s = lds + 16384;
    char* B3s = lds + 32768;

    const int K = DIMD;
    int row0 = blockIdx.y * 128;
    const uint16_t *b1 = W1, *b3 = W3;
    if (ROUTED) {
        if (row0 >= offs[NEXP]) return;
        int e = 0;
        while (row0 >= offs[e + 1]) ++e;
        size_t eo = (size_t)e * HIDN * DIMD;
        b1 += eo; b3 += eo;
    }
    int col0 = blockIdx.x * 128;

    int tid = threadIdx.x, lane = tid & 63;
    int wv = tid >> 6, wm = wv >> 1, wn = wv & 1;

    f32x4 acc1[4][4] = {};
    f32x4 acc3[4][4] = {};

    for (int kt = 0; kt < K; kt += 64) {
        __syncthreads();
        stage128x64(A  + (size_t)row0 * K + kt, K, As,  wv, lane);
        stage128x64(b1 + (size_t)col0 * K + kt, K, B1s, wv, lane);
        stage128x64(b3 + (size_t)col0 * K + kt, K, B3s, wv, lane);
        __syncthreads();   // compiler drains vmcnt before s_barrier

        #pragma unroll
        for (int s = 0; s < 2; ++s) {
            int cb = s * 64 + ((lane >> 4) << 4);
            s16x8 av[4];
            #pragma unroll
            for (int i = 0; i < 4; ++i)
                av[i] = *(const s16x8*)(As + swz(wm * 64 + i * 16 + (lane & 15), cb));
            #pragma unroll
            for (int j = 0; j < 4; ++j) {
                int br = wn * 64 + j * 16 + (lane & 15);
                s16x8 bv1 = *(const s16x8*)(B1s + swz(br, cb));
                s16x8 bv3 = *(const s16x8*)(B3s + swz(br, cb));
                #pragma unroll
                for (int i = 0; i < 4; ++i) {
                    acc1[i][j] = __builtin_amdgcn_mfma_f32_16x16x32_bf16(av[i], bv1, acc1[i][j], 0, 0, 0);
                    acc3[i][j] = __builtin_amdgcn_mfma_f32_16x16x32_bf16(av[i], bv3, acc3[i][j], 0, 0, 0);
                }
            }
        }
    }

    #pragma unroll
    for (int i = 0; i < 4; ++i) {
        #pragma unroll
        for (int j = 0; j < 4; ++j) {
            #pragma unroll
            for (int rg = 0; rg < 4; ++rg) {
                int row = row0 + wm * 64 + i * 16 + ((lane >> 4) << 2) + rg;
                int col = col0 + wn * 64 + j * 16 + (lane & 15);
                float a1 = acc1[i][j][rg];
                float a3 = acc3[i][j][rg];
                float hv = (a1 / (1.f + __expf(-a1))) * a3;   // silu(a1)*a3
                H[(size_t)row * ldh + col] = f2bf(hv);
            }
        }
    }
}

// GEMM2: C[M,1024] = A[M,K] (bf16) * B^T (bf16), B rows indexed with per-kSplit expert stride.
// ROUTED=1: expert from offs, bf16 store to H2g. ROUTED=0: f32 accumulate into out.
template<int ROUTED>
__global__ __launch_bounds__(256, 3)
void gemm2_kernel(const uint16_t* __restrict__ A, int lda,
                  const uint16_t* __restrict__ W2, void* __restrict__ Cout,
                  const int* __restrict__ offs,
                  int K, int kSplit, long long expStride) {
    __shared__ __align__(16) char lds[32768];
    char* As = lds;
    char* Bs = lds + 16384;

    int row0 = blockIdx.y * 128;
    const uint16_t* b2 = W2;
    if (ROUTED) {
        if (row0 >= offs[NEXP]) return;
        int e = 0;
        while (row0 >= offs[e + 1]) ++e;
        b2 += (size_t)e * DIMD * HIDN;
    }
    int col0 = blockIdx.x * 128;

    int tid = threadIdx.x, lane = tid & 63;
    int wv = tid >> 6, wm = wv >> 1, wn = wv & 1;

    f32x4 acc[4][4] = {};

    for (int kt = 0; kt < K; kt += 64) {
        const uint16_t* bb = b2 + (size_t)(kt / kSplit) * expStride + (kt % kSplit);
        __syncthreads();
        stage128x64(A  + (size_t)row0 * lda + kt, lda, As, wv, lane);
        stage128x64(bb + (size_t)col0 * kSplit, kSplit, Bs, wv, lane);
        __syncthreads();

        #pragma unroll
        for (int s = 0; s < 2; ++s) {
            int cb = s * 64 + ((lane >> 4) << 4);
            s16x8 av[4];
            #pragma unroll
            for (int i = 0; i < 4; ++i)
                av[i] = *(const s16x8*)(As + swz(wm * 64 + i * 16 + (lane & 15), cb));
            #pragma unroll
            for (int j = 0; j < 4; ++j) {
                s16x8 bv = *(const s16x8*)(Bs + swz(wn * 64 + j * 16 + (lane & 15), cb));
                #pragma unroll
                for (int i = 0; i < 4; ++i)
                    acc[i][j] = __builtin_amdgcn_mfma_f32_16x16x32_bf16(av[i], bv, acc[i][j], 0, 0, 0);
            }
        }
    }

    #pragma unroll
    for (int i = 0; i < 4; ++i) {
        #pragma unroll
        for (int j = 0; j < 4; ++j) {
            #pragma unroll
            for (int rg = 0; rg < 4; ++rg) {
                int row = row0 + wm * 64 + i * 16 + ((lane >> 4) << 2) + rg;
                int col = col0 + wn * 64 + j * 16 + (lane & 15);
                float v = acc[i][j][rg];
                if (ROUTED) ((uint16_t*)Cout)[(size_t)row * DIMD + col] = f2bf(v);
                else        ((float*)Cout)[(size_t)row * DIMD + col] += v;
            }
        }
    }
}

// ---------------- launch ----------------

extern "C" void kernel_launch(void* const* d_in, const int* in_sizes, int n_in,
                              void* d_out, int out_size, void* d_ws, size_t ws_size,
                              hipStream_t stream) {
    const float* x   = (const float*)d_in[0];
    const float* rw  = (const float*)d_in[1];
    const float* eb  = (const float*)d_in[2];
    const float* w1  = (const float*)d_in[3];
    const float* w3  = (const float*)d_in[4];
    const float* w2  = (const float*)d_in[5];
    const float* sw1 = (const float*)d_in[6];
    const float* sw3 = (const float*)d_in[7];
    const float* sw2 = (const float*)d_in[8];
    float* out = (float*)d_out;

    const int EW = NEXP * HIDN * DIMD;   // 16,777,216 elements per routed weight
    const int SW = 2 * HIDN * DIMD;      //  4,194,304 elements per shared weight

    char* ws = (char*)d_ws;
    size_t off = 0;
    auto alloc = [&](size_t b) { char* p = ws + off; off = (off + b + 255) & ~(size_t)255; return p; };
    uint16_t* xb  = (uint16_t*)alloc((size_t)T_TOK * DIMD * 2);   // x in bf16
    uint16_t* Xg  = (uint16_t*)alloc((size_t)RMAX * DIMD * 2);    // gathered tokens
    uint16_t* Hg  = (uint16_t*)alloc((size_t)RMAX * HIDN * 2);    // hidden (reused for shared, ldh=4096)
    uint16_t* H2g = (uint16_t*)alloc((size_t)RMAX * DIMD * 2);    // routed expert outputs
    uint16_t* w1b = (uint16_t*)alloc((size_t)EW * 2);
    uint16_t* w3b = (uint16_t*)alloc((size_t)EW * 2);
    uint16_t* w2b = (uint16_t*)alloc((size_t)EW * 2);
    uint16_t* sw1b = (uint16_t*)alloc((size_t)SW * 2);
    uint16_t* sw3b = (uint16_t*)alloc((size_t)SW * 2);
    uint16_t* sw2b = (uint16_t*)alloc((size_t)SW * 2);
    int*   sel    = (int*)  alloc(T_TOK * 2 * 4);
    float* wgt    = (float*)alloc(T_TOK * 2 * 4);
    int*   row_of = (int*)  alloc(T_TOK * 2 * 4);
    int*   cnt    = (int*)  alloc(64);
    int*   fill   = (int*)  alloc(64);
    int*   offs   = (int*)  alloc(64);

    hipMemsetAsync(cnt, 0, 64, stream);
    hipMemsetAsync(fill, 0, 64, stream);
    hipMemsetAsync(Xg, 0, (size_t)RMAX * DIMD * 2, stream);      // zero pad rows
    hipMemsetAsync(out, 0, (size_t)out_size * sizeof(float), stream);

    // all f32 -> bf16 conversions in one HBM-bound pass
    CvtArgs ca;
    ca.s[0] = w1;  ca.d[0] = w1b;  ca.nq[0] = EW / 4;
    ca.s[1] = w3;  ca.d[1] = w3b;  ca.nq[1] = EW / 4;
    ca.s[2] = w2;  ca.d[2] = w2b;  ca.nq[2] = EW / 4;
    ca.s[3] = sw1; ca.d[3] = sw1b; ca.nq[3] = SW / 4;
    ca.s[4] = sw3; ca.d[4] = sw3b; ca.nq[4] = SW / 4;
    ca.s[5] = sw2; ca.d[5] = sw2b; ca.nq[5] = SW / 4;
    ca.s[6] = x;   ca.d[6] = xb;   ca.nq[6] = T_TOK * DIMD / 4;
    cvt_all_kernel<<<2048, 256, 0, stream>>>(ca);

    router_kernel<<<T_TOK, 64, 0, stream>>>(x, rw, eb, sel, wgt);
    count_kernel<<<32, 256, 0, stream>>>(sel, cnt);
    offs_kernel<<<1, 1, 0, stream>>>(cnt, offs);
    assign_kernel<<<32, 256, 0, stream>>>(sel, offs, fill, row_of);
    gather_kernel<<<T_TOK * 2, 128, 0, stream>>>(xb, row_of, Xg);

    // routed experts: h = silu(Xg w1^T) * (Xg w3^T); H2g = h w2^T
    gemm13_kernel<1><<<dim3(HIDN / 128, RMAX / 128), 256, 0, stream>>>(Xg, w1b, w3b, Hg, HIDN, offs);
    gemm2_kernel<1><<<dim3(DIMD / 128, RMAX / 128), 256, 0, stream>>>(Hg, HIDN, w2b, (void*)H2g, offs,
                                                                      HIDN, HIDN, 0);
    combine_kernel<<<T_TOK, 128, 0, stream>>>(H2g, row_of, wgt, out);

    // shared experts folded into one GEMM pair: N-concat for GEMM1, K-concat for GEMM2
    gemm13_kernel<0><<<dim3((2 * HIDN) / 128, T_TOK / 128), 256, 0, stream>>>(xb, sw1b, sw3b, Hg, 2 * HIDN, nullptr);
    gemm2_kernel<0><<<dim3(DIMD / 128, T_TOK / 128), 256, 0, stream>>>(Hg, 2 * HIDN, sw2b, (void*)out, nullptr,
                                                                       2 * HIDN, HIDN, (long long)DIMD * HIDN);
}

// Round 4
// 572.631 us; speedup vs baseline: 1.2272x; 1.2272x over previous
//
#include <hip/hip_runtime.h>
#include <stdint.h>

#define T_TOK 4096
#define DIMD  1024
#define HIDN  2048
#define NEXP  8
#define RMAX  9216   // 8192 slots + 8*128 max alignment padding

typedef float f32x4 __attribute__((ext_vector_type(4)));
typedef short s16x8 __attribute__((ext_vector_type(8)));

__device__ __forceinline__ uint16_t f2bf(float f) {
    uint32_t u = __builtin_bit_cast(uint32_t, f);
    u += 0x7fffu + ((u >> 16) & 1u);
    return (uint16_t)(u >> 16);
}
__device__ __forceinline__ float bf2f(uint32_t h) {
    return __builtin_bit_cast(float, h << 16);
}
__device__ __forceinline__ uint32_t pk2(float a, float b) {
    return (uint32_t)f2bf(a) | ((uint32_t)f2bf(b) << 16);
}
// swizzled LDS byte offset: 128B row pitch, XOR row bits into 16B-granule slot
__device__ __forceinline__ int swz(int r, int cbyte) {
    return r * 128 + (cbyte ^ ((r & 7) << 4));
}
// async global->LDS, 16B per lane, LDS dest = base + lane*16 (wave-uniform base)
__device__ __forceinline__ void gload16(const void* g, void* l) {
    __builtin_amdgcn_global_load_lds(
        (const __attribute__((address_space(1))) void*)g,
        (__attribute__((address_space(3))) void*)l, 16, 0, 0);
}
// Stage a 128x64 bf16 tile (16KB) into LDS with st-16 swizzle.
// LDS dest is linear (slot s at byte 16*s); global source is inverse-swizzled
// so that a swz(r,cb) read returns element (r, cb). 4 issues per lane.
__device__ __forceinline__ void stage128x64(const uint16_t* gbase, int ldk,
                                            char* lds, int wv, int lane) {
    #pragma unroll
    for (int i = 0; i < 4; ++i) {
        int s = (wv * 4 + i) * 64 + lane;
        int row = s >> 3;
        int cb = ((s & 7) << 4) ^ ((row & 7) << 4);
        gload16(gbase + (size_t)row * ldk + (cb >> 1), lds + ((wv * 4 + i) << 10));
    }
}

// ---------------- small kernels ----------------

struct CvtArgs {
    const float* s[7];
    uint16_t*    d[7];
    int          nq[7];
};

__global__ void cvt_all_kernel(CvtArgs a) {
    int base = blockIdx.x * blockDim.x + threadIdx.x;
    int stride = gridDim.x * blockDim.x;
    #pragma unroll
    for (int seg = 0; seg < 7; ++seg) {
        const float4* sp = (const float4*)a.s[seg];
        uint2* dp = (uint2*)a.d[seg];
        int n = a.nq[seg];
        for (int i = base; i < n; i += stride) {
            float4 v = sp[i];
            uint2 o; o.x = pk2(v.x, v.y); o.y = pk2(v.z, v.w);
            dp[i] = o;
        }
    }
}

__global__ void router_kernel(const float* __restrict__ x, const float* __restrict__ rw,
                              const float* __restrict__ bias,
                              int* __restrict__ sel, float* __restrict__ wgt,
                              int* __restrict__ cnt) {
    int t = blockIdx.x;
    int lane = threadIdx.x;            // 64 threads = 1 wave
    int e = lane & 7, seg = lane >> 3; // 8 lanes per expert, 8 segments of 128
    const float* xr = x + (size_t)t * DIMD + seg * 128;
    const float* wr = rw + (size_t)e * DIMD + seg * 128;
    float s = 0.f;
    #pragma unroll 8
    for (int i = 0; i < 128; ++i) s += xr[i] * wr[i];
    s += __shfl_xor(s, 8, 64);
    s += __shfl_xor(s, 16, 64);
    s += __shfl_xor(s, 32, 64);
    __shared__ float lg[8];
    if (lane < 8) lg[lane] = s + bias[lane];
    __syncthreads();
    if (lane == 0) {
        float l0 = -1e30f; int i0 = 0;
        #pragma unroll
        for (int i = 0; i < 8; ++i) { float v = lg[i]; if (v > l0) { l0 = v; i0 = i; } }
        float l1 = -1e30f; int i1 = 0;
        #pragma unroll
        for (int i = 0; i < 8; ++i) { if (i == i0) continue; float v = lg[i]; if (v > l1) { l1 = v; i1 = i; } }
        float e1 = expf(l1 - l0);      // l0 >= l1 -> e1 <= 1
        float d = 1.f + e1;
        sel[t * 2] = i0; sel[t * 2 + 1] = i1;
        wgt[t * 2] = 1.f / d; wgt[t * 2 + 1] = e1 / d;
        atomicAdd(&cnt[i0], 1);
        atomicAdd(&cnt[i1], 1);
    }
}

__global__ void offs_kernel(const int* __restrict__ cnt, int* __restrict__ offs) {
    if (threadIdx.x == 0 && blockIdx.x == 0) {
        int o = 0;
        for (int e = 0; e < NEXP; ++e) { offs[e] = o; o += (cnt[e] + 127) & ~127; }
        offs[NEXP] = o;
    }
}

__global__ void assign_kernel(const int* __restrict__ sel, const int* __restrict__ offs,
                              int* __restrict__ fill, int* __restrict__ row_of) {
    int i = blockIdx.x * blockDim.x + threadIdx.x;
    if (i < T_TOK * 2) {
        int e = sel[i];
        row_of[i] = offs[e] + atomicAdd(&fill[e], 1);
    }
}

__global__ void gather_kernel(const uint16_t* __restrict__ xb, const int* __restrict__ row_of,
                              uint16_t* __restrict__ Xg) {
    int slot = blockIdx.x;
    int pos = row_of[slot];
    int t = slot >> 1;
    const uint4* src = (const uint4*)(xb + (size_t)t * DIMD);
    uint4* dst = (uint4*)(Xg + (size_t)pos * DIMD);
    dst[threadIdx.x] = src[threadIdx.x];   // 128 thr * 16B = 2048B row
}

__global__ void combine_kernel(const uint16_t* __restrict__ H2g, const int* __restrict__ row_of,
                               const float* __restrict__ wgt, float* __restrict__ out) {
    int t = blockIdx.x;
    int c = threadIdx.x * 8;   // 128 threads * 8 cols
    int r0 = row_of[t * 2], r1 = row_of[t * 2 + 1];
    float w0 = wgt[t * 2], w1 = wgt[t * 2 + 1];
    uint4 a = *(const uint4*)(H2g + (size_t)r0 * DIMD + c);
    uint4 b = *(const uint4*)(H2g + (size_t)r1 * DIMD + c);
    float* o = out + (size_t)t * DIMD + c;
    o[0] += w0 * bf2f(a.x & 0xffffu) + w1 * bf2f(b.x & 0xffffu);
    o[1] += w0 * bf2f(a.x >> 16)     + w1 * bf2f(b.x >> 16);
    o[2] += w0 * bf2f(a.y & 0xffffu) + w1 * bf2f(b.y & 0xffffu);
    o[3] += w0 * bf2f(a.y >> 16)     + w1 * bf2f(b.y >> 16);
    o[4] += w0 * bf2f(a.z & 0xffffu) + w1 * bf2f(b.z & 0xffffu);
    o[5] += w0 * bf2f(a.z >> 16)     + w1 * bf2f(b.z >> 16);
    o[6] += w0 * bf2f(a.w & 0xffffu) + w1 * bf2f(b.w & 0xffffu);
    o[7] += w0 * bf2f(a.w >> 16)     + w1 * bf2f(b.w >> 16);
}

// ---------------- GEMM kernels ----------------
// 128x128 tile, BK=64, 4 waves in 2x2, each wave 64x64 via 4x4 frags of 16x16x32 MFMA.
// All operands bf16; staging via global_load_lds (linear LDS dest, inverse-swizzled src).
// Grid: x = col tile (fast -> weight panels pinned per XCD since ncol%8==0),
//       y = row tile (slow -> A panel shared by the consecutive col blocks).

template<int ROUTED>
__global__ __launch_bounds__(256, 2)   // 2 blocks/CU: gemm13 needs 128 acc regs, (256,3) spills
void gemm13_kernel(const uint16_t* __restrict__ A,
                   const uint16_t* __restrict__ W1, const uint16_t* __restrict__ W3,
                   uint16_t* __restrict__ H, int ldh,
                   const int* __restrict__ offs) {
    __shared__ __align__(16) char lds[49152];
    char* As  = lds;
    char* B1s = lds + 16384;
    char* B3s = lds + 32768;

    const int K = DIMD;
    int row0 = blockIdx.y * 128;
    const uint16_t *b1 = W1, *b3 = W3;
    if (ROUTED) {
        if (row0 >= offs[NEXP]) return;
        int e = 0;
        while (row0 >= offs[e + 1]) ++e;
        size_t eo = (size_t)e * HIDN * DIMD;
        b1 += eo; b3 += eo;
    }
    int col0 = blockIdx.x * 128;

    int tid = threadIdx.x, lane = tid & 63;
    int wv = tid >> 6, wm = wv >> 1, wn = wv & 1;

    f32x4 acc1[4][4] = {};
    f32x4 acc3[4][4] = {};

    for (int kt = 0; kt < K; kt += 64) {
        __syncthreads();
        stage128x64(A  + (size_t)row0 * K + kt, K, As,  wv, lane);
        stage128x64(b1 + (size_t)col0 * K + kt, K, B1s, wv, lane);
        stage128x64(b3 + (size_t)col0 * K + kt, K, B3s, wv, lane);
        __syncthreads();   // compiler drains vmcnt before s_barrier

        #pragma unroll
        for (int s = 0; s < 2; ++s) {
            int cb = s * 64 + ((lane >> 4) << 4);
            s16x8 av[4];
            #pragma unroll
            for (int i = 0; i < 4; ++i)
                av[i] = *(const s16x8*)(As + swz(wm * 64 + i * 16 + (lane & 15), cb));
            #pragma unroll
            for (int j = 0; j < 4; ++j) {
                int br = wn * 64 + j * 16 + (lane & 15);
                s16x8 bv1 = *(const s16x8*)(B1s + swz(br, cb));
                s16x8 bv3 = *(const s16x8*)(B3s + swz(br, cb));
                #pragma unroll
                for (int i = 0; i < 4; ++i) {
                    acc1[i][j] = __builtin_amdgcn_mfma_f32_16x16x32_bf16(av[i], bv1, acc1[i][j], 0, 0, 0);
                    acc3[i][j] = __builtin_amdgcn_mfma_f32_16x16x32_bf16(av[i], bv3, acc3[i][j], 0, 0, 0);
                }
            }
        }
    }

    #pragma unroll
    for (int i = 0; i < 4; ++i) {
        #pragma unroll
        for (int j = 0; j < 4; ++j) {
            #pragma unroll
            for (int rg = 0; rg < 4; ++rg) {
                int row = row0 + wm * 64 + i * 16 + ((lane >> 4) << 2) + rg;
                int col = col0 + wn * 64 + j * 16 + (lane & 15);
                float a1 = acc1[i][j][rg];
                float a3 = acc3[i][j][rg];
                float hv = (a1 / (1.f + __expf(-a1))) * a3;   // silu(a1)*a3
                H[(size_t)row * ldh + col] = f2bf(hv);
            }
        }
    }
}

// GEMM2: C[M,1024] = A[M,K] (bf16) * B^T (bf16), B rows indexed with per-kSplit expert stride.
// ROUTED=1: expert from offs, bf16 store to H2g. ROUTED=0: f32 accumulate into out.
template<int ROUTED>
__global__ __launch_bounds__(256, 3)
void gemm2_kernel(const uint16_t* __restrict__ A, int lda,
                  const uint16_t* __restrict__ W2, void* __restrict__ Cout,
                  const int* __restrict__ offs,
                  int K, int kSplit, long long expStride) {
    __shared__ __align__(16) char lds[32768];
    char* As = lds;
    char* Bs = lds + 16384;

    int row0 = blockIdx.y * 128;
    const uint16_t* b2 = W2;
    if (ROUTED) {
        if (row0 >= offs[NEXP]) return;
        int e = 0;
        while (row0 >= offs[e + 1]) ++e;
        b2 += (size_t)e * DIMD * HIDN;
    }
    int col0 = blockIdx.x * 128;

    int tid = threadIdx.x, lane = tid & 63;
    int wv = tid >> 6, wm = wv >> 1, wn = wv & 1;

    f32x4 acc[4][4] = {};

    for (int kt = 0; kt < K; kt += 64) {
        const uint16_t* bb = b2 + (size_t)(kt / kSplit) * expStride + (kt % kSplit);
        __syncthreads();
        stage128x64(A  + (size_t)row0 * lda + kt, lda, As, wv, lane);
        stage128x64(bb + (size_t)col0 * kSplit, kSplit, Bs, wv, lane);
        __syncthreads();

        #pragma unroll
        for (int s = 0; s < 2; ++s) {
            int cb = s * 64 + ((lane >> 4) << 4);
            s16x8 av[4];
            #pragma unroll
            for (int i = 0; i < 4; ++i)
                av[i] = *(const s16x8*)(As + swz(wm * 64 + i * 16 + (lane & 15), cb));
            #pragma unroll
            for (int j = 0; j < 4; ++j) {
                s16x8 bv = *(const s16x8*)(Bs + swz(wn * 64 + j * 16 + (lane & 15), cb));
                #pragma unroll
                for (int i = 0; i < 4; ++i)
                    acc[i][j] = __builtin_amdgcn_mfma_f32_16x16x32_bf16(av[i], bv, acc[i][j], 0, 0, 0);
            }
        }
    }

    #pragma unroll
    for (int i = 0; i < 4; ++i) {
        #pragma unroll
        for (int j = 0; j < 4; ++j) {
            #pragma unroll
            for (int rg = 0; rg < 4; ++rg) {
                int row = row0 + wm * 64 + i * 16 + ((lane >> 4) << 2) + rg;
                int col = col0 + wn * 64 + j * 16 + (lane & 15);
                float v = acc[i][j][rg];
                if (ROUTED) ((uint16_t*)Cout)[(size_t)row * DIMD + col] = f2bf(v);
                else        ((float*)Cout)[(size_t)row * DIMD + col] += v;
            }
        }
    }
}

// ---------------- launch ----------------

extern "C" void kernel_launch(void* const* d_in, const int* in_sizes, int n_in,
                              void* d_out, int out_size, void* d_ws, size_t ws_size,
                              hipStream_t stream) {
    const float* x   = (const float*)d_in[0];
    const float* rw  = (const float*)d_in[1];
    const float* eb  = (const float*)d_in[2];
    const float* w1  = (const float*)d_in[3];
    const float* w3  = (const float*)d_in[4];
    const float* w2  = (const float*)d_in[5];
    const float* sw1 = (const float*)d_in[6];
    const float* sw3 = (const float*)d_in[7];
    const float* sw2 = (const float*)d_in[8];
    float* out = (float*)d_out;

    const int EW = NEXP * HIDN * DIMD;   // 16,777,216 elements per routed weight
    const int SW = 2 * HIDN * DIMD;      //  4,194,304 elements per shared weight

    char* ws = (char*)d_ws;
    size_t off = 0;
    auto alloc = [&](size_t b) { char* p = ws + off; off = (off + b + 255) & ~(size_t)255; return p; };
    uint16_t* xb  = (uint16_t*)alloc((size_t)T_TOK * DIMD * 2);   // x in bf16
    uint16_t* Xg  = (uint16_t*)alloc((size_t)RMAX * DIMD * 2);    // gathered tokens
    uint16_t* Hg  = (uint16_t*)alloc((size_t)RMAX * HIDN * 2);    // hidden (reused for shared, ldh=4096)
    uint16_t* H2g = (uint16_t*)alloc((size_t)RMAX * DIMD * 2);    // routed expert outputs
    uint16_t* w1b = (uint16_t*)alloc((size_t)EW * 2);
    uint16_t* w3b = (uint16_t*)alloc((size_t)EW * 2);
    uint16_t* w2b = (uint16_t*)alloc((size_t)EW * 2);
    uint16_t* sw1b = (uint16_t*)alloc((size_t)SW * 2);
    uint16_t* sw3b = (uint16_t*)alloc((size_t)SW * 2);
    uint16_t* sw2b = (uint16_t*)alloc((size_t)SW * 2);
    int*   sel    = (int*)  alloc(T_TOK * 2 * 4);
    float* wgt    = (float*)alloc(T_TOK * 2 * 4);
    int*   row_of = (int*)  alloc(T_TOK * 2 * 4);
    int*   cnt    = (int*)  alloc(64);
    int*   fill   = (int*)  alloc(64);
    int*   offs   = (int*)  alloc(64);

    hipMemsetAsync(cnt, 0, 64, stream);
    hipMemsetAsync(fill, 0, 64, stream);
    hipMemsetAsync(Xg, 0, (size_t)RMAX * DIMD * 2, stream);      // zero pad rows
    hipMemsetAsync(out, 0, (size_t)out_size * sizeof(float), stream);

    // all f32 -> bf16 conversions in one HBM-bound pass
    CvtArgs ca;
    ca.s[0] = w1;  ca.d[0] = w1b;  ca.nq[0] = EW / 4;
    ca.s[1] = w3;  ca.d[1] = w3b;  ca.nq[1] = EW / 4;
    ca.s[2] = w2;  ca.d[2] = w2b;  ca.nq[2] = EW / 4;
    ca.s[3] = sw1; ca.d[3] = sw1b; ca.nq[3] = SW / 4;
    ca.s[4] = sw3; ca.d[4] = sw3b; ca.nq[4] = SW / 4;
    ca.s[5] = sw2; ca.d[5] = sw2b; ca.nq[5] = SW / 4;
    ca.s[6] = x;   ca.d[6] = xb;   ca.nq[6] = T_TOK * DIMD / 4;
    cvt_all_kernel<<<2048, 256, 0, stream>>>(ca);

    router_kernel<<<T_TOK, 64, 0, stream>>>(x, rw, eb, sel, wgt, cnt);
    offs_kernel<<<1, 1, 0, stream>>>(cnt, offs);
    assign_kernel<<<32, 256, 0, stream>>>(sel, offs, fill, row_of);
    gather_kernel<<<T_TOK * 2, 128, 0, stream>>>(xb, row_of, Xg);

    // routed experts: h = silu(Xg w1^T) * (Xg w3^T); H2g = h w2^T
    gemm13_kernel<1><<<dim3(HIDN / 128, RMAX / 128), 256, 0, stream>>>(Xg, w1b, w3b, Hg, HIDN, offs);
    gemm2_kernel<1><<<dim3(DIMD / 128, RMAX / 128), 256, 0, stream>>>(Hg, HIDN, w2b, (void*)H2g, offs,
                                                                      HIDN, HIDN, 0);
    combine_kernel<<<T_TOK, 128, 0, stream>>>(H2g, row_of, wgt, out);

    // shared experts folded into one GEMM pair: N-concat for GEMM1, K-concat for GEMM2
    gemm13_kernel<0><<<dim3((2 * HIDN) / 128, T_TOK / 128), 256, 0, stream>>>(xb, sw1b, sw3b, Hg, 2 * HIDN, nullptr);
    gemm2_kernel<0><<<dim3(DIMD / 128, T_TOK / 128), 256, 0, stream>>>(Hg, 2 * HIDN, sw2b, (void*)out, nullptr,
                                                                       2 * HIDN, HIDN, (long long)DIMD * HIDN);
}

// Round 5
// 557.037 us; speedup vs baseline: 1.2616x; 1.0280x over previous
//
#include <hip/hip_runtime.h>
#include <stdint.h>

#define T_TOK 4096
#define DIMD  1024
#define HIDN  2048
#define NEXP  8
#define RMAX  9216   // 8192 slots + 8*128 max alignment padding

typedef float f32x4 __attribute__((ext_vector_type(4)));
typedef short s16x8 __attribute__((ext_vector_type(8)));

__device__ __forceinline__ uint16_t f2bf(float f) {
    uint32_t u = __builtin_bit_cast(uint32_t, f);
    u += 0x7fffu + ((u >> 16) & 1u);
    return (uint16_t)(u >> 16);
}
__device__ __forceinline__ float bf2f(uint32_t h) {
    return __builtin_bit_cast(float, h << 16);
}
__device__ __forceinline__ uint32_t pk2(float a, float b) {
    return (uint32_t)f2bf(a) | ((uint32_t)f2bf(b) << 16);
}
// swizzled LDS byte offset: 128B row pitch, XOR row bits into 16B-granule slot
__device__ __forceinline__ int swz(int r, int cbyte) {
    return r * 128 + (cbyte ^ ((r & 7) << 4));
}
// async global->LDS, 16B per lane, LDS dest = base + lane*16 (wave-uniform base)
__device__ __forceinline__ void gload16(const void* g, void* l) {
    __builtin_amdgcn_global_load_lds(
        (const __attribute__((address_space(1))) void*)g,
        (__attribute__((address_space(3))) void*)l, 16, 0, 0);
}
// Stage a 128x64 bf16 tile (16KB) into LDS with st-16 swizzle.
// LDS dest is linear (slot s at byte 16*s); global source is inverse-swizzled
// so that a swz(r,cb) read returns element (r, cb). 4 issues per lane.
__device__ __forceinline__ void stage128x64(const uint16_t* gbase, int ldk,
                                            char* lds, int wv, int lane) {
    #pragma unroll
    for (int i = 0; i < 4; ++i) {
        int s = (wv * 4 + i) * 64 + lane;
        int row = s >> 3;
        int cb = ((s & 7) << 4) ^ ((row & 7) << 4);
        gload16(gbase + (size_t)row * ldk + (cb >> 1), lds + ((wv * 4 + i) << 10));
    }
}

// ---------------- small kernels ----------------

struct CvtArgs {
    const float* s[7];
    uint16_t*    d[7];
    int          nq[7];
};

__global__ void cvt_all_kernel(CvtArgs a) {
    int base = blockIdx.x * blockDim.x + threadIdx.x;
    int stride = gridDim.x * blockDim.x;
    #pragma unroll
    for (int seg = 0; seg < 7; ++seg) {
        const float4* sp = (const float4*)a.s[seg];
        uint2* dp = (uint2*)a.d[seg];
        int n = a.nq[seg];
        for (int i = base; i < n; i += stride) {
            float4 v = sp[i];
            uint2 o; o.x = pk2(v.x, v.y); o.y = pk2(v.z, v.w);
            dp[i] = o;
        }
    }
}

// Router: 128 blocks x 256 thr; rw staged in LDS; 1 wave = 8 tokens.
// Lane i reads x[t][i*4..i*4+3] (coalesced float4), dots vs 8 experts from LDS,
// 6-level butterfly reduces all 8 logits; lane 0 does top-2 + softmax + counts.
__global__ __launch_bounds__(256)
void router_kernel(const float* __restrict__ x, const float* __restrict__ rw,
                   const float* __restrict__ bias,
                   int* __restrict__ sel, float* __restrict__ wgt,
                   int* __restrict__ cnt) {
    __shared__ float rws[NEXP * DIMD];
    int tid = threadIdx.x;
    for (int i = tid; i < NEXP * DIMD / 4; i += 256)
        ((float4*)rws)[i] = ((const float4*)rw)[i];
    __syncthreads();

    int wid = tid >> 6, lane = tid & 63;
    float b[NEXP];
    #pragma unroll
    for (int e = 0; e < NEXP; ++e) b[e] = bias[e];

    int t0 = (blockIdx.x * 4 + wid) * 8;
    for (int j = 0; j < 8; ++j) {
        int t = t0 + j;
        const float4* xr = (const float4*)(x + (size_t)t * DIMD);
        float p[NEXP] = {};
        #pragma unroll
        for (int c = 0; c < 4; ++c) {
            float4 xv = xr[c * 64 + lane];
            #pragma unroll
            for (int e = 0; e < NEXP; ++e) {
                float4 wv = *(const float4*)(rws + e * DIMD + c * 256 + lane * 4);
                p[e] += xv.x * wv.x + xv.y * wv.y + xv.z * wv.z + xv.w * wv.w;
            }
        }
        #pragma unroll
        for (int off = 32; off >= 1; off >>= 1) {
            #pragma unroll
            for (int e = 0; e < NEXP; ++e) p[e] += __shfl_xor(p[e], off, 64);
        }
        if (lane == 0) {
            #pragma unroll
            for (int e = 0; e < NEXP; ++e) p[e] += b[e];
            float l0 = -1e30f; int i0 = 0;
            #pragma unroll
            for (int e = 0; e < NEXP; ++e) { if (p[e] > l0) { l0 = p[e]; i0 = e; } }
            float l1 = -1e30f; int i1 = 0;
            #pragma unroll
            for (int e = 0; e < NEXP; ++e) { if (e == i0) continue; if (p[e] > l1) { l1 = p[e]; i1 = e; } }
            float e1 = expf(l1 - l0);      // l0 >= l1 -> e1 <= 1
            float d = 1.f + e1;
            sel[t * 2] = i0; sel[t * 2 + 1] = i1;
            wgt[t * 2] = 1.f / d; wgt[t * 2 + 1] = e1 / d;
            atomicAdd(&cnt[i0], 1);
            atomicAdd(&cnt[i1], 1);
        }
    }
}

__global__ void offs_kernel(const int* __restrict__ cnt, int* __restrict__ offs) {
    if (threadIdx.x == 0 && blockIdx.x == 0) {
        int o = 0;
        for (int e = 0; e < NEXP; ++e) { offs[e] = o; o += (cnt[e] + 127) & ~127; }
        offs[NEXP] = o;
    }
}

__global__ void assign_kernel(const int* __restrict__ sel, const int* __restrict__ offs,
                              int* __restrict__ fill, int* __restrict__ row_of) {
    int i = blockIdx.x * blockDim.x + threadIdx.x;
    if (i < T_TOK * 2) {
        int e = sel[i];
        row_of[i] = offs[e] + atomicAdd(&fill[e], 1);
    }
}

__global__ void gather_kernel(const uint16_t* __restrict__ xb, const int* __restrict__ row_of,
                              uint16_t* __restrict__ Xg) {
    int slot = blockIdx.x;
    int pos = row_of[slot];
    int t = slot >> 1;
    const uint4* src = (const uint4*)(xb + (size_t)t * DIMD);
    uint4* dst = (uint4*)(Xg + (size_t)pos * DIMD);
    dst[threadIdx.x] = src[threadIdx.x];   // 128 thr * 16B = 2048B row
}

__global__ void combine_kernel(const uint16_t* __restrict__ H2g, const int* __restrict__ row_of,
                               const float* __restrict__ wgt, float* __restrict__ out) {
    int t = blockIdx.x;
    int c = threadIdx.x * 8;   // 128 threads * 8 cols
    int r0 = row_of[t * 2], r1 = row_of[t * 2 + 1];
    float w0 = wgt[t * 2], w1 = wgt[t * 2 + 1];
    uint4 a = *(const uint4*)(H2g + (size_t)r0 * DIMD + c);
    uint4 b = *(const uint4*)(H2g + (size_t)r1 * DIMD + c);
    float* o = out + (size_t)t * DIMD + c;
    o[0] += w0 * bf2f(a.x & 0xffffu) + w1 * bf2f(b.x & 0xffffu);
    o[1] += w0 * bf2f(a.x >> 16)     + w1 * bf2f(b.x >> 16);
    o[2] += w0 * bf2f(a.y & 0xffffu) + w1 * bf2f(b.y & 0xffffu);
    o[3] += w0 * bf2f(a.y >> 16)     + w1 * bf2f(b.y >> 16);
    o[4] += w0 * bf2f(a.z & 0xffffu) + w1 * bf2f(b.z & 0xffffu);
    o[5] += w0 * bf2f(a.z >> 16)     + w1 * bf2f(b.z >> 16);
    o[6] += w0 * bf2f(a.w & 0xffffu) + w1 * bf2f(b.w & 0xffffu);
    o[7] += w0 * bf2f(a.w >> 16)     + w1 * bf2f(b.w >> 16);
}

// ---------------- GEMM kernels ----------------
// 128x128 tile, BK=64, 4 waves in 2x2, each wave 64x64 via 4x4 frags of 16x16x32 MFMA.
// All operands bf16; staging via global_load_lds (linear LDS dest, inverse-swizzled src).
// Grid: x = col tile (fast -> weight panels pinned per XCD since ncol%8==0),
//       y = row tile (slow -> A panel shared by the consecutive col blocks).

template<int ROUTED>
__global__ __launch_bounds__(256, 2)   // 2 blocks/CU: gemm13 needs 128 acc regs, (256,3) spills
void gemm13_kernel(const uint16_t* __restrict__ A,
                   const uint16_t* __restrict__ W1, const uint16_t* __restrict__ W3,
                   uint16_t* __restrict__ H, int ldh,
                   const int* __restrict__ offs) {
    __shared__ __align__(16) char lds[49152];
    char* As  = lds;
    char* B1s = lds + 16384;
    char* B3s = lds + 32768;

    const int K = DIMD;
    int row0 = blockIdx.y * 128;
    const uint16_t *b1 = W1, *b3 = W3;
    if (ROUTED) {
        if (row0 >= offs[NEXP]) return;
        int e = 0;
        while (row0 >= offs[e + 1]) ++e;
        size_t eo = (size_t)e * HIDN * DIMD;
        b1 += eo; b3 += eo;
    }
    int col0 = blockIdx.x * 128;

    int tid = threadIdx.x, lane = tid & 63;
    int wv = tid >> 6, wm = wv >> 1, wn = wv & 1;

    f32x4 acc1[4][4] = {};
    f32x4 acc3[4][4] = {};

    for (int kt = 0; kt < K; kt += 64) {
        __syncthreads();
        stage128x64(A  + (size_t)row0 * K + kt, K, As,  wv, lane);
        stage128x64(b1 + (size_t)col0 * K + kt, K, B1s, wv, lane);
        stage128x64(b3 + (size_t)col0 * K + kt, K, B3s, wv, lane);
        __syncthreads();   // compiler drains vmcnt before s_barrier

        #pragma unroll
        for (int s = 0; s < 2; ++s) {
            int cb = s * 64 + ((lane >> 4) << 4);
            s16x8 av[4];
            #pragma unroll
            for (int i = 0; i < 4; ++i)
                av[i] = *(const s16x8*)(As + swz(wm * 64 + i * 16 + (lane & 15), cb));
            #pragma unroll
            for (int j = 0; j < 4; ++j) {
                int br = wn * 64 + j * 16 + (lane & 15);
                s16x8 bv1 = *(const s16x8*)(B1s + swz(br, cb));
                s16x8 bv3 = *(const s16x8*)(B3s + swz(br, cb));
                #pragma unroll
                for (int i = 0; i < 4; ++i) {
                    acc1[i][j] = __builtin_amdgcn_mfma_f32_16x16x32_bf16(av[i], bv1, acc1[i][j], 0, 0, 0);
                    acc3[i][j] = __builtin_amdgcn_mfma_f32_16x16x32_bf16(av[i], bv3, acc3[i][j], 0, 0, 0);
                }
            }
        }
    }

    #pragma unroll
    for (int i = 0; i < 4; ++i) {
        #pragma unroll
        for (int j = 0; j < 4; ++j) {
            #pragma unroll
            for (int rg = 0; rg < 4; ++rg) {
                int row = row0 + wm * 64 + i * 16 + ((lane >> 4) << 2) + rg;
                int col = col0 + wn * 64 + j * 16 + (lane & 15);
                float a1 = acc1[i][j][rg];
                float a3 = acc3[i][j][rg];
                float hv = (a1 / (1.f + __expf(-a1))) * a3;   // silu(a1)*a3
                H[(size_t)row * ldh + col] = f2bf(hv);
            }
        }
    }
}

// GEMM2: C[M,1024] = A[M,K] (bf16) * B^T (bf16), B rows indexed with per-kSplit expert stride.
// ROUTED=1: expert from offs, bf16 store to H2g. ROUTED=0: f32 accumulate into out.
template<int ROUTED>
__global__ __launch_bounds__(256, 3)
void gemm2_kernel(const uint16_t* __restrict__ A, int lda,
                  const uint16_t* __restrict__ W2, void* __restrict__ Cout,
                  const int* __restrict__ offs,
                  int K, int kSplit, long long expStride) {
    __shared__ __align__(16) char lds[32768];
    char* As = lds;
    char* Bs = lds + 16384;

    int row0 = blockIdx.y * 128;
    const uint16_t* b2 = W2;
    if (ROUTED) {
        if (row0 >= offs[NEXP]) return;
        int e = 0;
        while (row0 >= offs[e + 1]) ++e;
        b2 += (size_t)e * DIMD * HIDN;
    }
    int col0 = blockIdx.x * 128;

    int tid = threadIdx.x, lane = tid & 63;
    int wv = tid >> 6, wm = wv >> 1, wn = wv & 1;

    f32x4 acc[4][4] = {};

    for (int kt = 0; kt < K; kt += 64) {
        const uint16_t* bb = b2 + (size_t)(kt / kSplit) * expStride + (kt % kSplit);
        __syncthreads();
        stage128x64(A  + (size_t)row0 * lda + kt, lda, As, wv, lane);
        stage128x64(bb + (size_t)col0 * kSplit, kSplit, Bs, wv, lane);
        __syncthreads();

        #pragma unroll
        for (int s = 0; s < 2; ++s) {
            int cb = s * 64 + ((lane >> 4) << 4);
            s16x8 av[4];
            #pragma unroll
            for (int i = 0; i < 4; ++i)
                av[i] = *(const s16x8*)(As + swz(wm * 64 + i * 16 + (lane & 15), cb));
            #pragma unroll
            for (int j = 0; j < 4; ++j) {
                s16x8 bv = *(const s16x8*)(Bs + swz(wn * 64 + j * 16 + (lane & 15), cb));
                #pragma unroll
                for (int i = 0; i < 4; ++i)
                    acc[i][j] = __builtin_amdgcn_mfma_f32_16x16x32_bf16(av[i], bv, acc[i][j], 0, 0, 0);
            }
        }
    }

    #pragma unroll
    for (int i = 0; i < 4; ++i) {
        #pragma unroll
        for (int j = 0; j < 4; ++j) {
            #pragma unroll
            for (int rg = 0; rg < 4; ++rg) {
                int row = row0 + wm * 64 + i * 16 + ((lane >> 4) << 2) + rg;
                int col = col0 + wn * 64 + j * 16 + (lane & 15);
                float v = acc[i][j][rg];
                if (ROUTED) ((uint16_t*)Cout)[(size_t)row * DIMD + col] = f2bf(v);
                else        ((float*)Cout)[(size_t)row * DIMD + col] += v;
            }
        }
    }
}

// ---------------- launch ----------------

extern "C" void kernel_launch(void* const* d_in, const int* in_sizes, int n_in,
                              void* d_out, int out_size, void* d_ws, size_t ws_size,
                              hipStream_t stream) {
    const float* x   = (const float*)d_in[0];
    const float* rw  = (const float*)d_in[1];
    const float* eb  = (const float*)d_in[2];
    const float* w1  = (const float*)d_in[3];
    const float* w3  = (const float*)d_in[4];
    const float* w2  = (const float*)d_in[5];
    const float* sw1 = (const float*)d_in[6];
    const float* sw3 = (const float*)d_in[7];
    const float* sw2 = (const float*)d_in[8];
    float* out = (float*)d_out;

    const int EW = NEXP * HIDN * DIMD;   // 16,777,216 elements per routed weight
    const int SW = 2 * HIDN * DIMD;      //  4,194,304 elements per shared weight

    char* ws = (char*)d_ws;
    size_t off = 0;
    auto alloc = [&](size_t b) { char* p = ws + off; off = (off + b + 255) & ~(size_t)255; return p; };
    uint16_t* xb  = (uint16_t*)alloc((size_t)T_TOK * DIMD * 2);   // x in bf16
    uint16_t* Xg  = (uint16_t*)alloc((size_t)RMAX * DIMD * 2);    // gathered tokens
    uint16_t* Hg  = (uint16_t*)alloc((size_t)RMAX * HIDN * 2);    // hidden (reused for shared, ldh=4096)
    uint16_t* H2g = (uint16_t*)alloc((size_t)RMAX * DIMD * 2);    // routed expert outputs
    uint16_t* w1b = (uint16_t*)alloc((size_t)EW * 2);
    uint16_t* w3b = (uint16_t*)alloc((size_t)EW * 2);
    uint16_t* w2b = (uint16_t*)alloc((size_t)EW * 2);
    uint16_t* sw1b = (uint16_t*)alloc((size_t)SW * 2);
    uint16_t* sw3b = (uint16_t*)alloc((size_t)SW * 2);
    uint16_t* sw2b = (uint16_t*)alloc((size_t)SW * 2);
    int*   sel    = (int*)  alloc(T_TOK * 2 * 4);
    float* wgt    = (float*)alloc(T_TOK * 2 * 4);
    int*   row_of = (int*)  alloc(T_TOK * 2 * 4);
    int*   cnt    = (int*)  alloc(64);
    int*   fill   = (int*)  alloc(64);
    int*   offs   = (int*)  alloc(64);

    hipMemsetAsync(cnt, 0, 64, stream);
    hipMemsetAsync(fill, 0, 64, stream);
    hipMemsetAsync(Xg, 0, (size_t)RMAX * DIMD * 2, stream);      // zero pad rows
    hipMemsetAsync(out, 0, (size_t)out_size * sizeof(float), stream);

    // all f32 -> bf16 conversions in one HBM-bound pass
    CvtArgs ca;
    ca.s[0] = w1;  ca.d[0] = w1b;  ca.nq[0] = EW / 4;
    ca.s[1] = w3;  ca.d[1] = w3b;  ca.nq[1] = EW / 4;
    ca.s[2] = w2;  ca.d[2] = w2b;  ca.nq[2] = EW / 4;
    ca.s[3] = sw1; ca.d[3] = sw1b; ca.nq[3] = SW / 4;
    ca.s[4] = sw3; ca.d[4] = sw3b; ca.nq[4] = SW / 4;
    ca.s[5] = sw2; ca.d[5] = sw2b; ca.nq[5] = SW / 4;
    ca.s[6] = x;   ca.d[6] = xb;   ca.nq[6] = T_TOK * DIMD / 4;
    cvt_all_kernel<<<2048, 256, 0, stream>>>(ca);

    router_kernel<<<128, 256, 0, stream>>>(x, rw, eb, sel, wgt, cnt);
    offs_kernel<<<1, 1, 0, stream>>>(cnt, offs);
    assign_kernel<<<32, 256, 0, stream>>>(sel, offs, fill, row_of);
    gather_kernel<<<T_TOK * 2, 128, 0, stream>>>(xb, row_of, Xg);

    // routed experts: h = silu(Xg w1^T) * (Xg w3^T); H2g = h w2^T
    gemm13_kernel<1><<<dim3(HIDN / 128, RMAX / 128), 256, 0, stream>>>(Xg, w1b, w3b, Hg, HIDN, offs);
    gemm2_kernel<1><<<dim3(DIMD / 128, RMAX / 128), 256, 0, stream>>>(Hg, HIDN, w2b, (void*)H2g, offs,
                                                                      HIDN, HIDN, 0);
    combine_kernel<<<T_TOK, 128, 0, stream>>>(H2g, row_of, wgt, out);

    // shared experts folded into one GEMM pair: N-concat for GEMM1, K-concat for GEMM2
    gemm13_kernel<0><<<dim3((2 * HIDN) / 128, T_TOK / 128), 256, 0, stream>>>(xb, sw1b, sw3b, Hg, 2 * HIDN, nullptr);
    gemm2_kernel<0><<<dim3(DIMD / 128, T_TOK / 128), 256, 0, stream>>>(Hg, 2 * HIDN, sw2b, (void*)out, nullptr,
                                                                       2 * HIDN, HIDN, (long long)DIMD * HIDN);
}

// Round 6
// 473.455 us; speedup vs baseline: 1.4843x; 1.1765x over previous
//
#include <hip/hip_runtime.h>
#include <stdint.h>

#define T_TOK 4096
#define DIMD  1024
#define HIDN  2048
#define NEXP  8
#define RMAX  9216                  // routed: 8192 slots + 8*128 alignment pad
#define RROWS (RMAX + 2 * T_TOK)    // + 2 shared-expert segments = 17408 rows max

typedef float f32x4 __attribute__((ext_vector_type(4)));
typedef short s16x8 __attribute__((ext_vector_type(8)));

__device__ __forceinline__ uint16_t f2bf(float f) {
    uint32_t u = __builtin_bit_cast(uint32_t, f);
    u += 0x7fffu + ((u >> 16) & 1u);
    return (uint16_t)(u >> 16);
}
__device__ __forceinline__ float bf2f(uint32_t h) {
    return __builtin_bit_cast(float, h << 16);
}
__device__ __forceinline__ uint32_t pk2(float a, float b) {
    return (uint32_t)f2bf(a) | ((uint32_t)f2bf(b) << 16);
}
// swizzled LDS byte offset: 128B row pitch, XOR row bits into 16B-granule slot
__device__ __forceinline__ int swz(int r, int cbyte) {
    return r * 128 + (cbyte ^ ((r & 7) << 4));
}
// async global->LDS, 16B per lane, LDS dest = base + lane*16 (wave-uniform base)
__device__ __forceinline__ void gload16(const void* g, void* l) {
    __builtin_amdgcn_global_load_lds(
        (const __attribute__((address_space(1))) void*)g,
        (__attribute__((address_space(3))) void*)l, 16, 0, 0);
}
// Stage a 128x64 bf16 tile (16KB) into LDS with st-16 swizzle.
// LDS dest linear; global source inverse-swizzled so swz(r,cb) reads elem (r,cb).
__device__ __forceinline__ void stage128x64(const uint16_t* gbase, int ldk,
                                            char* lds, int wv, int lane) {
    #pragma unroll
    for (int i = 0; i < 4; ++i) {
        int s = (wv * 4 + i) * 64 + lane;
        int row = s >> 3;
        int cb = ((s & 7) << 4) ^ ((row & 7) << 4);
        gload16(gbase + (size_t)row * ldk + (cb >> 1), lds + ((wv * 4 + i) << 10));
    }
}

// ---------------- small kernels ----------------

struct CvtArgs {
    const float* s[7];
    uint16_t*    d[7];
    int          nq[7];
};

__global__ void cvt_all_kernel(CvtArgs a) {
    int base = blockIdx.x * blockDim.x + threadIdx.x;
    int stride = gridDim.x * blockDim.x;
    #pragma unroll
    for (int seg = 0; seg < 7; ++seg) {
        const float4* sp = (const float4*)a.s[seg];
        uint2* dp = (uint2*)a.d[seg];
        int n = a.nq[seg];
        for (int i = base; i < n; i += stride) {
            float4 v = sp[i];
            uint2 o; o.x = pk2(v.x, v.y); o.y = pk2(v.z, v.w);
            dp[i] = o;
        }
    }
}

// Router: 128 blocks x 256 thr; rw staged in LDS; 1 wave = 8 tokens.
__global__ __launch_bounds__(256)
void router_kernel(const float* __restrict__ x, const float* __restrict__ rw,
                   const float* __restrict__ bias,
                   int* __restrict__ sel, float* __restrict__ wgt,
                   int* __restrict__ cnt) {
    __shared__ float rws[NEXP * DIMD];
    int tid = threadIdx.x;
    for (int i = tid; i < NEXP * DIMD / 4; i += 256)
        ((float4*)rws)[i] = ((const float4*)rw)[i];
    __syncthreads();

    int wid = tid >> 6, lane = tid & 63;
    float b[NEXP];
    #pragma unroll
    for (int e = 0; e < NEXP; ++e) b[e] = bias[e];

    int t0 = (blockIdx.x * 4 + wid) * 8;
    for (int j = 0; j < 8; ++j) {
        int t = t0 + j;
        const float4* xr = (const float4*)(x + (size_t)t * DIMD);
        float p[NEXP] = {};
        #pragma unroll
        for (int c = 0; c < 4; ++c) {
            float4 xv = xr[c * 64 + lane];
            #pragma unroll
            for (int e = 0; e < NEXP; ++e) {
                float4 wv = *(const float4*)(rws + e * DIMD + c * 256 + lane * 4);
                p[e] += xv.x * wv.x + xv.y * wv.y + xv.z * wv.z + xv.w * wv.w;
            }
        }
        #pragma unroll
        for (int off = 32; off >= 1; off >>= 1) {
            #pragma unroll
            for (int e = 0; e < NEXP; ++e) p[e] += __shfl_xor(p[e], off, 64);
        }
        if (lane == 0) {
            #pragma unroll
            for (int e = 0; e < NEXP; ++e) p[e] += b[e];
            float l0 = -1e30f; int i0 = 0;
            #pragma unroll
            for (int e = 0; e < NEXP; ++e) { if (p[e] > l0) { l0 = p[e]; i0 = e; } }
            float l1 = -1e30f; int i1 = 0;
            #pragma unroll
            for (int e = 0; e < NEXP; ++e) { if (e == i0) continue; if (p[e] > l1) { l1 = p[e]; i1 = e; } }
            float e1 = expf(l1 - l0);      // l0 >= l1 -> e1 <= 1
            float d = 1.f + e1;
            sel[t * 2] = i0; sel[t * 2 + 1] = i1;
            wgt[t * 2] = 1.f / d; wgt[t * 2 + 1] = e1 / d;
            atomicAdd(&cnt[i0], 1);
            atomicAdd(&cnt[i1], 1);
        }
    }
}

__global__ void offs_kernel(const int* __restrict__ cnt, int* __restrict__ offs) {
    if (threadIdx.x == 0 && blockIdx.x == 0) {
        int o = 0;
        for (int e = 0; e < NEXP; ++e) { offs[e] = o; o += (cnt[e] + 127) & ~127; }
        offs[NEXP] = o;
    }
}

// slot -> row, and row -> token (tok). Also fills tok for the shared segments.
__global__ void assign_kernel(const int* __restrict__ sel, const int* __restrict__ offs,
                              int* __restrict__ fill, int* __restrict__ row_of,
                              int* __restrict__ tok) {
    int i = blockIdx.x * blockDim.x + threadIdx.x;
    if (i < 2 * T_TOK) {
        int e = sel[i];
        int r = offs[e] + atomicAdd(&fill[e], 1);
        row_of[i] = r;
        tok[r] = i >> 1;
    } else if (i < 4 * T_TOK) {
        int j = i - 2 * T_TOK;                       // 0..8191: shared rows
        tok[offs[NEXP] + j] = j & (T_TOK - 1);
    }
}

// out[t] = w0*H2[r0] + w1*H2[r1] + H2[s0] + H2[s1]  (pure write)
__global__ void combine_kernel(const uint16_t* __restrict__ H2, const int* __restrict__ row_of,
                               const float* __restrict__ wgt, const int* __restrict__ offs,
                               float* __restrict__ out) {
    int t = blockIdx.x;
    int c = threadIdx.x * 8;   // 128 threads * 8 cols
    int r0 = row_of[t * 2], r1 = row_of[t * 2 + 1];
    int s0 = offs[NEXP] + t, s1 = s0 + T_TOK;
    float w0 = wgt[t * 2], w1 = wgt[t * 2 + 1];
    uint4 a = *(const uint4*)(H2 + (size_t)r0 * DIMD + c);
    uint4 b = *(const uint4*)(H2 + (size_t)r1 * DIMD + c);
    uint4 u = *(const uint4*)(H2 + (size_t)s0 * DIMD + c);
    uint4 v = *(const uint4*)(H2 + (size_t)s1 * DIMD + c);
    float4 o0, o1;
    o0.x = w0 * bf2f(a.x & 0xffffu) + w1 * bf2f(b.x & 0xffffu) + bf2f(u.x & 0xffffu) + bf2f(v.x & 0xffffu);
    o0.y = w0 * bf2f(a.x >> 16)     + w1 * bf2f(b.x >> 16)     + bf2f(u.x >> 16)     + bf2f(v.x >> 16);
    o0.z = w0 * bf2f(a.y & 0xffffu) + w1 * bf2f(b.y & 0xffffu) + bf2f(u.y & 0xffffu) + bf2f(v.y & 0xffffu);
    o0.w = w0 * bf2f(a.y >> 16)     + w1 * bf2f(b.y >> 16)     + bf2f(u.y >> 16)     + bf2f(v.y >> 16);
    o1.x = w0 * bf2f(a.z & 0xffffu) + w1 * bf2f(b.z & 0xffffu) + bf2f(u.z & 0xffffu) + bf2f(v.z & 0xffffu);
    o1.y = w0 * bf2f(a.z >> 16)     + w1 * bf2f(b.z >> 16)     + bf2f(u.z >> 16)     + bf2f(v.z >> 16);
    o1.z = w0 * bf2f(a.w & 0xffffu) + w1 * bf2f(b.w & 0xffffu) + bf2f(u.w & 0xffffu) + bf2f(v.w & 0xffffu);
    o1.w = w0 * bf2f(a.w >> 16)     + w1 * bf2f(b.w >> 16)     + bf2f(u.w >> 16)     + bf2f(v.w >> 16);
    float* o = out + (size_t)t * DIMD + c;
    *(float4*)o = o0;
    *(float4*)(o + 4) = o1;
}

// ---------------- unified GEMM kernels ----------------
// Row space: [0, offs[8]) routed (expert via offs), [offs[8], offs[8]+8192) shared
// (expert 8/9, 4096 rows each). A rows resolved through tok[] (gather fused into
// staging: global_load_lds source address is per-lane).
// Grid: x = col tile (fast, %8==0 -> weight panels pinned per XCD), y = row tile.

__global__ __launch_bounds__(256, 2)   // 2 blocks/CU: 128 acc regs, (256,3) spills
void gemm13_kernel(const uint16_t* __restrict__ xb, const int* __restrict__ tok,
                   const uint16_t* __restrict__ W1, const uint16_t* __restrict__ W3,
                   uint16_t* __restrict__ H, const int* __restrict__ offs) {
    __shared__ __align__(16) char lds[49152];
    char* As  = lds;
    char* B1s = lds + 16384;
    char* B3s = lds + 32768;

    const int K = DIMD;
    int row0 = blockIdx.y * 128;
    int rsh = row0 - offs[NEXP];
    int e;
    if (rsh >= 0) {
        if (rsh >= 2 * T_TOK) return;
        e = NEXP + (rsh >> 12);
    } else {
        e = 0;
        while (row0 >= offs[e + 1]) ++e;
    }
    const uint16_t* b1 = W1 + (size_t)e * HIDN * DIMD;
    const uint16_t* b3 = W3 + (size_t)e * HIDN * DIMD;
    int col0 = blockIdx.x * 128;

    int tid = threadIdx.x, lane = tid & 63;
    int wv = tid >> 6, wm = wv >> 1, wn = wv & 1;

    // per-lane A staging bases (token-indirected), fixed across K
    size_t abase[4];
    #pragma unroll
    for (int i = 0; i < 4; ++i) {
        int s = (wv * 4 + i) * 64 + lane;
        int row = s >> 3;
        int cb = ((s & 7) << 4) ^ ((row & 7) << 4);
        abase[i] = (size_t)tok[row0 + row] * DIMD + (cb >> 1);
    }

    f32x4 acc1[4][4] = {};
    f32x4 acc3[4][4] = {};

    for (int kt = 0; kt < K; kt += 64) {
        __syncthreads();
        #pragma unroll
        for (int i = 0; i < 4; ++i)
            gload16(xb + abase[i] + kt, As + ((wv * 4 + i) << 10));
        stage128x64(b1 + (size_t)col0 * K + kt, K, B1s, wv, lane);
        stage128x64(b3 + (size_t)col0 * K + kt, K, B3s, wv, lane);
        __syncthreads();   // compiler drains vmcnt before s_barrier

        #pragma unroll
        for (int s = 0; s < 2; ++s) {
            int cb = s * 64 + ((lane >> 4) << 4);
            s16x8 av[4];
            #pragma unroll
            for (int i = 0; i < 4; ++i)
                av[i] = *(const s16x8*)(As + swz(wm * 64 + i * 16 + (lane & 15), cb));
            #pragma unroll
            for (int j = 0; j < 4; ++j) {
                int br = wn * 64 + j * 16 + (lane & 15);
                s16x8 bv1 = *(const s16x8*)(B1s + swz(br, cb));
                s16x8 bv3 = *(const s16x8*)(B3s + swz(br, cb));
                #pragma unroll
                for (int i = 0; i < 4; ++i) {
                    acc1[i][j] = __builtin_amdgcn_mfma_f32_16x16x32_bf16(av[i], bv1, acc1[i][j], 0, 0, 0);
                    acc3[i][j] = __builtin_amdgcn_mfma_f32_16x16x32_bf16(av[i], bv3, acc3[i][j], 0, 0, 0);
                }
            }
        }
    }

    #pragma unroll
    for (int i = 0; i < 4; ++i) {
        #pragma unroll
        for (int j = 0; j < 4; ++j) {
            #pragma unroll
            for (int rg = 0; rg < 4; ++rg) {
                int row = row0 + wm * 64 + i * 16 + ((lane >> 4) << 2) + rg;
                int col = col0 + wn * 64 + j * 16 + (lane & 15);
                float a1 = acc1[i][j][rg];
                float a3 = acc3[i][j][rg];
                float hv = (a1 / (1.f + __expf(-a1))) * a3;   // silu(a1)*a3
                H[(size_t)row * HIDN + col] = f2bf(hv);
            }
        }
    }
}

// GEMM2: H2[r, 0..1024) = Hg[r, :] @ w2[e]^T, bf16 out, same row space as gemm13.
__global__ __launch_bounds__(256, 3)
void gemm2_kernel(const uint16_t* __restrict__ Hg,
                  const uint16_t* __restrict__ W2, uint16_t* __restrict__ H2,
                  const int* __restrict__ offs) {
    __shared__ __align__(16) char lds[32768];
    char* As = lds;
    char* Bs = lds + 16384;

    const int K = HIDN;
    int row0 = blockIdx.y * 128;
    int rsh = row0 - offs[NEXP];
    int e;
    if (rsh >= 0) {
        if (rsh >= 2 * T_TOK) return;
        e = NEXP + (rsh >> 12);
    } else {
        e = 0;
        while (row0 >= offs[e + 1]) ++e;
    }
    const uint16_t* b2 = W2 + (size_t)e * DIMD * HIDN;
    int col0 = blockIdx.x * 128;

    int tid = threadIdx.x, lane = tid & 63;
    int wv = tid >> 6, wm = wv >> 1, wn = wv & 1;

    f32x4 acc[4][4] = {};

    for (int kt = 0; kt < K; kt += 64) {
        __syncthreads();
        stage128x64(Hg + (size_t)row0 * K + kt, K, As, wv, lane);
        stage128x64(b2 + (size_t)col0 * K + kt, K, Bs, wv, lane);
        __syncthreads();

        #pragma unroll
        for (int s = 0; s < 2; ++s) {
            int cb = s * 64 + ((lane >> 4) << 4);
            s16x8 av[4];
            #pragma unroll
            for (int i = 0; i < 4; ++i)
                av[i] = *(const s16x8*)(As + swz(wm * 64 + i * 16 + (lane & 15), cb));
            #pragma unroll
            for (int j = 0; j < 4; ++j) {
                s16x8 bv = *(const s16x8*)(Bs + swz(wn * 64 + j * 16 + (lane & 15), cb));
                #pragma unroll
                for (int i = 0; i < 4; ++i)
                    acc[i][j] = __builtin_amdgcn_mfma_f32_16x16x32_bf16(av[i], bv, acc[i][j], 0, 0, 0);
            }
        }
    }

    #pragma unroll
    for (int i = 0; i < 4; ++i) {
        #pragma unroll
        for (int j = 0; j < 4; ++j) {
            #pragma unroll
            for (int rg = 0; rg < 4; ++rg) {
                int row = row0 + wm * 64 + i * 16 + ((lane >> 4) << 2) + rg;
                int col = col0 + wn * 64 + j * 16 + (lane & 15);
                H2[(size_t)row * DIMD + col] = f2bf(acc[i][j][rg]);
            }
        }
    }
}

// ---------------- launch ----------------

extern "C" void kernel_launch(void* const* d_in, const int* in_sizes, int n_in,
                              void* d_out, int out_size, void* d_ws, size_t ws_size,
                              hipStream_t stream) {
    const float* x   = (const float*)d_in[0];
    const float* rw  = (const float*)d_in[1];
    const float* eb  = (const float*)d_in[2];
    const float* w1  = (const float*)d_in[3];
    const float* w3  = (const float*)d_in[4];
    const float* w2  = (const float*)d_in[5];
    const float* sw1 = (const float*)d_in[6];
    const float* sw3 = (const float*)d_in[7];
    const float* sw2 = (const float*)d_in[8];
    float* out = (float*)d_out;

    const int EW = NEXP * HIDN * DIMD;   // elements in 8 routed expert weights
    const int SW = 2 * HIDN * DIMD;      // elements in 2 shared expert weights

    char* ws = (char*)d_ws;
    size_t off = 0;
    auto alloc = [&](size_t b) { char* p = ws + off; off = (off + b + 255) & ~(size_t)255; return p; };
    uint16_t* xb    = (uint16_t*)alloc((size_t)T_TOK * DIMD * 2);    // x in bf16
    uint16_t* Hg    = (uint16_t*)alloc((size_t)RROWS * HIDN * 2);    // hidden, unified rows
    uint16_t* H2    = (uint16_t*)alloc((size_t)RROWS * DIMD * 2);    // FFN outputs, unified rows
    uint16_t* w1all = (uint16_t*)alloc((size_t)(EW + SW) * 2);       // 10 experts
    uint16_t* w3all = (uint16_t*)alloc((size_t)(EW + SW) * 2);
    uint16_t* w2all = (uint16_t*)alloc((size_t)(EW + SW) * 2);
    int*   sel    = (int*)  alloc(T_TOK * 2 * 4);
    float* wgt    = (float*)alloc(T_TOK * 2 * 4);
    int*   row_of = (int*)  alloc(T_TOK * 2 * 4);
    int*   tok    = (int*)  alloc(RROWS * 4);
    int*   cnt    = (int*)  alloc(64);
    int*   fill   = (int*)  alloc(64);
    int*   offs   = (int*)  alloc(64);

    hipMemsetAsync(cnt, 0, 64, stream);
    hipMemsetAsync(fill, 0, 64, stream);
    hipMemsetAsync(tok, 0, RROWS * 4, stream);   // pad rows -> token 0 (harmless)

    // all f32 -> bf16 conversions in one HBM-bound pass; shared experts appended
    // as experts 8..9 of the unified weight buffers
    CvtArgs ca;
    ca.s[0] = w1;  ca.d[0] = w1all;      ca.nq[0] = EW / 4;
    ca.s[1] = sw1; ca.d[1] = w1all + EW; ca.nq[1] = SW / 4;
    ca.s[2] = w3;  ca.d[2] = w3all;      ca.nq[2] = EW / 4;
    ca.s[3] = sw3; ca.d[3] = w3all + EW; ca.nq[3] = SW / 4;
    ca.s[4] = w2;  ca.d[4] = w2all;      ca.nq[4] = EW / 4;
    ca.s[5] = sw2; ca.d[5] = w2all + EW; ca.nq[5] = SW / 4;
    ca.s[6] = x;   ca.d[6] = xb;         ca.nq[6] = T_TOK * DIMD / 4;
    cvt_all_kernel<<<2048, 256, 0, stream>>>(ca);

    router_kernel<<<128, 256, 0, stream>>>(x, rw, eb, sel, wgt, cnt);
    offs_kernel<<<1, 1, 0, stream>>>(cnt, offs);
    assign_kernel<<<64, 256, 0, stream>>>(sel, offs, fill, row_of, tok);

    // unified expert FFN over all rows (routed segments + 2 shared segments)
    gemm13_kernel<<<dim3(HIDN / 128, RROWS / 128), 256, 0, stream>>>(xb, tok, w1all, w3all, Hg, offs);
    gemm2_kernel<<<dim3(DIMD / 128, RROWS / 128), 256, 0, stream>>>(Hg, w2all, H2, offs);

    combine_kernel<<<T_TOK, 128, 0, stream>>>(H2, row_of, wgt, offs, out);
}